// Round 13
// baseline (58.114 us; speedup 1.0000x reference)
//
#include <hip/hip_runtime.h>

// Problem: out[b,h,w,i,k] = inputs[b,h,w,i] * u[i,k],
//          u[i,k] = beta[i,k]^2 / sum_k beta[i,k]^2
// Shapes: inputs (4,256,256,32) f32, beta (32,8) f32, out (...,32,8) f32.
// Memory-bound: 268 MB write + 33.5 MB read. Floor ~44us (writes @6.9 +
// reads @6.3, phase-separated).
//
// Evidence (effective BW on 302 MB):
//   r6  nt+mixed, 2048 blk grid-stride : 60.8us  ~5.0 TB/s
//   r11 plain+phase-sep, 2048 blk      : 62.6us  ~4.8
//   r12 plain+phase-sep, 512 blk, each a CONTIGUOUS 512 KiB sweep:
//                                        55.3us  ~5.5  <- stream count is
//                                                        the live lever
// Round-13: halve stream count again. 256 blocks (1/CU), each sweeping a
// contiguous 1 MiB output region; 128 KiB input slice staged to dynamic
// LDS (129 KiB/block -> 1 block/CU); plain stores; u via intra-row
// shuffles. Matches the fill kernel's ~4 waves/CU regime (6.9 TB/s).

#define DIMD 32
#define DIMK 8
#define CHUNKS_PER_BLOCK 65536   // f32x4 output chunks per block (1 MiB)
#define IN4_PER_BLOCK    8192    // f32x4 input per block (128 KiB)

typedef float f32x4 __attribute__((ext_vector_type(4)));

__global__ __launch_bounds__(256) void mass_proto_kernel(
    const float* __restrict__ inputs,
    const float* __restrict__ beta,
    float* __restrict__ out,
    int n4,       // total output f32x4 chunks
    int nelem4)   // total input f32x4s
{
    extern __shared__ __align__(16) float lds[];
    float* u  = lds;          // 256 floats (1 KiB)
    float* xf = lds + 256;    // 32768 floats (128 KiB) staged input
    f32x4* xin4 = reinterpret_cast<f32x4*>(xf);

    const int t = threadIdx.x;                  // 0..255
    const int b = blockIdx.x;
    const int cbase = b * CHUNKS_PER_BLOCK;     // output chunk base
    const int ibase = b * IN4_PER_BLOCK;        // input f32x4 base

    // ---- phase 1: stage contiguous 128 KiB input slice into LDS ----
    const f32x4* __restrict__ in4 = reinterpret_cast<const f32x4*>(inputs);
    if (ibase + IN4_PER_BLOCK <= nelem4) {
#pragma unroll 8
        for (int j = 0; j < IN4_PER_BLOCK / 256; ++j)
            xin4[j * 256 + t] = in4[ibase + j * 256 + t];
    } else {
#pragma unroll 8
        for (int j = 0; j < IN4_PER_BLOCK / 256; ++j) {
            const int g = ibase + j * 256 + t;
            xin4[j * 256 + t] = (g < nelem4) ? in4[g] : (f32x4)0.f;
        }
    }

    // ---- u[i,k] = beta^2 / rowsum(beta^2) via intra-row shuffles ----
    // rows of 8 threads never cross a wave boundary -> no extra barrier
    const float bv = beta[t];
    const float s2 = bv * bv;
    float sum = s2;
    sum += __shfl_xor(sum, 1);
    sum += __shfl_xor(sum, 2);
    sum += __shfl_xor(sum, 4);
    u[t] = s2 / sum;
    __syncthreads();                            // xin + u both ready

    // chunk index mod 64 == t mod 64 (CHUNKS_PER_BLOCK, 256 both %64==0)
    const f32x4 uu = reinterpret_cast<const f32x4*>(u)[t & 63];
    f32x4* __restrict__ out4 = reinterpret_cast<f32x4*>(out) + cbase;
    const int th = t >> 1;                      // LDS slot (2-way broadcast, free)

    // ---- phase 2: pure sequential write sweep over this block's 1 MiB ----
    if (cbase + CHUNKS_PER_BLOCK <= n4) {
#pragma unroll 8
        for (int j = 0; j < CHUNKS_PER_BLOCK / 256; ++j)
            out4[j * 256 + t] = xf[j * 128 + th] * uu;
    } else {
#pragma unroll 8
        for (int j = 0; j < CHUNKS_PER_BLOCK / 256; ++j) {
            const int c = j * 256 + t;
            if (cbase + c < n4) out4[c] = xf[j * 128 + th] * uu;
        }
    }
}

extern "C" void kernel_launch(void* const* d_in, const int* in_sizes, int n_in,
                              void* d_out, int out_size, void* d_ws, size_t ws_size,
                              hipStream_t stream) {
    const float* inputs = (const float*)d_in[0];  // (4,256,256,32)
    const float* beta   = (const float*)d_in[1];  // (32,8)
    float* out = (float*)d_out;                   // (4,256,256,32,8)

    const int n4 = out_size / 4;                  // 16,777,216 chunks
    const int nelem4 = in_sizes[0] / 4;           // 2,097,152 input f32x4
    const int blocks = (n4 + CHUNKS_PER_BLOCK - 1) / CHUNKS_PER_BLOCK;  // 256
    const size_t shmem = (256 + IN4_PER_BLOCK * 4) * sizeof(float);     // 129 KiB

    mass_proto_kernel<<<blocks, 256, shmem, stream>>>(inputs, beta, out, n4, nelem4);
}

// Round 14
// 55.260 us; speedup vs baseline: 1.0517x; 1.0517x over previous
//
#include <hip/hip_runtime.h>

// Problem: out[b,h,w,i,k] = inputs[b,h,w,i] * u[i,k],
//          u[i,k] = beta[i,k]^2 / sum_k beta[i,k]^2
// Shapes: inputs (4,256,256,32) f32, beta (32,8) f32, out (...,32,8) f32.
// Memory-bound: 268 MB write + 33.5 MB read. Floor ~44us.
//
// Evidence (302 MB effective):
//   r11 2048 blk, interleaved grid-stride, 32 w/CU : 62.6us
//   r12  512 blk x256t, contiguous 512KiB, 8 w/CU  : 55.3us  <- best
//   r13  256 blk x256t, contiguous 1MiB,   4 w/CU  : 58.1us  (too few waves)
// Round-14: hold stream count at 512 contiguous regions, double the waves:
// 512 blocks x 512 threads (2 blk/CU, 16 waves/CU). Separates write-phase
// wave-parallelism from stream fragmentation. Plain stores (nt proven
// slower), phase-separated LDS staging (64 KiB input slice per block).

#define DIMD 32
#define DIMK 8
#define THREADS 512
#define CHUNKS_PER_BLOCK 32768   // f32x4 output chunks per block (512 KiB)
#define IN4_PER_BLOCK    4096    // f32x4 input per block (64 KiB)

typedef float f32x4 __attribute__((ext_vector_type(4)));

__global__ __launch_bounds__(THREADS) void mass_proto_kernel(
    const float* __restrict__ inputs,
    const float* __restrict__ beta,
    float* __restrict__ out,
    int n4,       // total output f32x4 chunks
    int nelem4)   // total input f32x4s
{
    extern __shared__ __align__(16) float lds[];
    float* u  = lds;          // 256 floats (1 KiB)
    float* xf = lds + 256;    // 16384 floats (64 KiB) staged input
    f32x4* xin4 = reinterpret_cast<f32x4*>(xf);

    const int t = threadIdx.x;                  // 0..511
    const int b = blockIdx.x;
    const int cbase = b * CHUNKS_PER_BLOCK;     // output chunk base
    const int ibase = b * IN4_PER_BLOCK;        // input f32x4 base

    // ---- phase 1: stage contiguous 64 KiB input slice into LDS ----
    const f32x4* __restrict__ in4 = reinterpret_cast<const f32x4*>(inputs);
    if (ibase + IN4_PER_BLOCK <= nelem4) {
#pragma unroll
        for (int j = 0; j < IN4_PER_BLOCK / THREADS; ++j)   // 8 loads in flight
            xin4[j * THREADS + t] = in4[ibase + j * THREADS + t];
    } else {
#pragma unroll
        for (int j = 0; j < IN4_PER_BLOCK / THREADS; ++j) {
            const int g = ibase + j * THREADS + t;
            xin4[j * THREADS + t] = (g < nelem4) ? in4[g] : (f32x4)0.f;
        }
    }

    // ---- u[i,k] = beta^2 / rowsum(beta^2) via intra-row shuffles ----
    // rows of 8 lanes never cross a wave boundary; waves 0-3 fully active
    if (t < DIMD * DIMK) {
        const float bv = beta[t];
        const float s2 = bv * bv;
        float sum = s2;
        sum += __shfl_xor(sum, 1);
        sum += __shfl_xor(sum, 2);
        sum += __shfl_xor(sum, 4);
        u[t] = s2 / sum;
    }
    __syncthreads();                            // xin + u both ready

    // chunk index mod 64 == t mod 64 (CHUNKS_PER_BLOCK, THREADS both %64==0)
    const f32x4 uu = reinterpret_cast<const f32x4*>(u)[t & 63];
    f32x4* __restrict__ out4 = reinterpret_cast<f32x4*>(out) + cbase;
    const int th = t >> 1;                      // LDS slot (2-way broadcast, free)

    // ---- phase 2: pure sequential write sweep over this block's 512 KiB ----
    if (cbase + CHUNKS_PER_BLOCK <= n4) {
#pragma unroll 8
        for (int j = 0; j < CHUNKS_PER_BLOCK / THREADS; ++j)   // 64 trips
            out4[j * THREADS + t] = xf[j * (THREADS / 2) + th] * uu;
    } else {
#pragma unroll 8
        for (int j = 0; j < CHUNKS_PER_BLOCK / THREADS; ++j) {
            const int c = j * THREADS + t;
            if (cbase + c < n4) out4[c] = xf[j * (THREADS / 2) + th] * uu;
        }
    }
}

extern "C" void kernel_launch(void* const* d_in, const int* in_sizes, int n_in,
                              void* d_out, int out_size, void* d_ws, size_t ws_size,
                              hipStream_t stream) {
    const float* inputs = (const float*)d_in[0];  // (4,256,256,32)
    const float* beta   = (const float*)d_in[1];  // (32,8)
    float* out = (float*)d_out;                   // (4,256,256,32,8)

    const int n4 = out_size / 4;                  // 16,777,216 chunks
    const int nelem4 = in_sizes[0] / 4;           // 2,097,152 input f32x4
    const int blocks = (n4 + CHUNKS_PER_BLOCK - 1) / CHUNKS_PER_BLOCK;  // 512
    const size_t shmem = (256 + IN4_PER_BLOCK * 4) * sizeof(float);     // 65 KiB

    mass_proto_kernel<<<blocks, THREADS, shmem, stream>>>(inputs, beta, out, n4, nelem4);
}

// Round 15
// 55.248 us; speedup vs baseline: 1.0519x; 1.0002x over previous
//
#include <hip/hip_runtime.h>

// Problem: out[b,h,w,i,k] = inputs[b,h,w,i] * u[i,k],
//          u[i,k] = beta[i,k]^2 / sum_k beta[i,k]^2
// Shapes: inputs (4,256,256,32) f32, beta (32,8) f32, out (...,32,8) f32.
// Memory-bound: 268 MB write + 33.5 MB read. Floor ~44us.
//
// Evidence (302 MB effective):
//   r11 2048 blk, interleaved grid-stride, 32 w/CU : 62.6us
//   r12  512 blk x256t, contiguous 512KiB, 8 w/CU  : 55.3us  <- best
//   r13  256 blk x256t, contiguous 1MiB,   4 w/CU  : 58.1us  (too few waves)
// Round-14: hold stream count at 512 contiguous regions, double the waves:
// 512 blocks x 512 threads (2 blk/CU, 16 waves/CU). Separates write-phase
// wave-parallelism from stream fragmentation. Plain stores (nt proven
// slower), phase-separated LDS staging (64 KiB input slice per block).

#define DIMD 32
#define DIMK 8
#define THREADS 512
#define CHUNKS_PER_BLOCK 32768   // f32x4 output chunks per block (512 KiB)
#define IN4_PER_BLOCK    4096    // f32x4 input per block (64 KiB)

typedef float f32x4 __attribute__((ext_vector_type(4)));

__global__ __launch_bounds__(THREADS) void mass_proto_kernel(
    const float* __restrict__ inputs,
    const float* __restrict__ beta,
    float* __restrict__ out,
    int n4,       // total output f32x4 chunks
    int nelem4)   // total input f32x4s
{
    extern __shared__ __align__(16) float lds[];
    float* u  = lds;          // 256 floats (1 KiB)
    float* xf = lds + 256;    // 16384 floats (64 KiB) staged input
    f32x4* xin4 = reinterpret_cast<f32x4*>(xf);

    const int t = threadIdx.x;                  // 0..511
    const int b = blockIdx.x;
    const int cbase = b * CHUNKS_PER_BLOCK;     // output chunk base
    const int ibase = b * IN4_PER_BLOCK;        // input f32x4 base

    // ---- phase 1: stage contiguous 64 KiB input slice into LDS ----
    const f32x4* __restrict__ in4 = reinterpret_cast<const f32x4*>(inputs);
    if (ibase + IN4_PER_BLOCK <= nelem4) {
#pragma unroll
        for (int j = 0; j < IN4_PER_BLOCK / THREADS; ++j)   // 8 loads in flight
            xin4[j * THREADS + t] = in4[ibase + j * THREADS + t];
    } else {
#pragma unroll
        for (int j = 0; j < IN4_PER_BLOCK / THREADS; ++j) {
            const int g = ibase + j * THREADS + t;
            xin4[j * THREADS + t] = (g < nelem4) ? in4[g] : (f32x4)0.f;
        }
    }

    // ---- u[i,k] = beta^2 / rowsum(beta^2) via intra-row shuffles ----
    // rows of 8 lanes never cross a wave boundary; waves 0-3 fully active
    if (t < DIMD * DIMK) {
        const float bv = beta[t];
        const float s2 = bv * bv;
        float sum = s2;
        sum += __shfl_xor(sum, 1);
        sum += __shfl_xor(sum, 2);
        sum += __shfl_xor(sum, 4);
        u[t] = s2 / sum;
    }
    __syncthreads();                            // xin + u both ready

    // chunk index mod 64 == t mod 64 (CHUNKS_PER_BLOCK, THREADS both %64==0)
    const f32x4 uu = reinterpret_cast<const f32x4*>(u)[t & 63];
    f32x4* __restrict__ out4 = reinterpret_cast<f32x4*>(out) + cbase;
    const int th = t >> 1;                      // LDS slot (2-way broadcast, free)

    // ---- phase 2: pure sequential write sweep over this block's 512 KiB ----
    if (cbase + CHUNKS_PER_BLOCK <= n4) {
#pragma unroll 8
        for (int j = 0; j < CHUNKS_PER_BLOCK / THREADS; ++j)   // 64 trips
            out4[j * THREADS + t] = xf[j * (THREADS / 2) + th] * uu;
    } else {
#pragma unroll 8
        for (int j = 0; j < CHUNKS_PER_BLOCK / THREADS; ++j) {
            const int c = j * THREADS + t;
            if (cbase + c < n4) out4[c] = xf[j * (THREADS / 2) + th] * uu;
        }
    }
}

extern "C" void kernel_launch(void* const* d_in, const int* in_sizes, int n_in,
                              void* d_out, int out_size, void* d_ws, size_t ws_size,
                              hipStream_t stream) {
    const float* inputs = (const float*)d_in[0];  // (4,256,256,32)
    const float* beta   = (const float*)d_in[1];  // (32,8)
    float* out = (float*)d_out;                   // (4,256,256,32,8)

    const int n4 = out_size / 4;                  // 16,777,216 chunks
    const int nelem4 = in_sizes[0] / 4;           // 2,097,152 input f32x4
    const int blocks = (n4 + CHUNKS_PER_BLOCK - 1) / CHUNKS_PER_BLOCK;  // 512
    const size_t shmem = (256 + IN4_PER_BLOCK * 4) * sizeof(float);     // 65 KiB

    mass_proto_kernel<<<blocks, THREADS, shmem, stream>>>(inputs, beta, out, n4, nelem4);
}